// Round 2
// baseline (138.168 us; speedup 1.0000x reference)
//
#include <hip/hip_runtime.h>
#include <math.h>

// Persistent-span chunked parallel IIR (z-formulation):
//   z[i] = alpha*z[i-1] + d[i];  y[i] = d[i] - (1-alpha)*z[i-1]
// Each block owns a contiguous span (2 chunks of 8192) of a row. z carries
// EXACTLY across chunks within a span; the 2048-elem halo is paid once per
// span (read amp 1.125). Chunk t+1's x is prefetched into registers before
// chunk t's compute+stores.
// R2: occupancy lever. Grid = 16 x 64 = 1024 blocks, launch_bounds(512,6)
// -> <=85 VGPR -> 3 blocks/CU resident (24 waves/CU, was 16). rv[] dropped:
// exclusive lane scan comes from DPP wave_shr:1 (lane0 = 0 via bound_ctrl),
// saving 4 VGPR + 4 fma per chunk.
// Wave scans use DPP row_shr/row_bcast (VALU, no LDS traffic).
#define TPB 512
#define WAVES (TPB / 64)          // 8
#define PER_WAVE 1024             // elements per wave per chunk
#define CHUNK (WAVES * PER_WAVE)  // 8192
#define NB 16                     // blocks (spans) per row
#define HALO 2048                 // alpha^2048 ~ 2.9e-3, error << 0.1075 thr

typedef float v4f __attribute__((ext_vector_type(4)));

template<int CTRL, int RM, int BM, bool BC>
__device__ __forceinline__ float dppf(float v) {
    return __int_as_float(__builtin_amdgcn_update_dpp(
        0, __float_as_int(v), CTRL, RM, BM, BC));
}

__device__ __forceinline__ float readlane_f(float v, int l) {
    return __int_as_float(__builtin_amdgcn_readlane(__float_as_int(v), l));
}

// Weighted inclusive scan over 64 lanes: S_l = sum_{k<=l} m^(l-k) * v_k, m=A4.
// row_shr 1/2/4/8 (within-16 scan), row_bcast:15 (rows 1,3 += w1 * prev-row
// prefix), row_bcast:31 (rows 2,3 += w2 * S_31).
// w1 = m^((lane&15)+1), w2 = m^((lane&31)+1).
__device__ __forceinline__ float scan_iir(float v, float mo1, float mo2,
                                          float mo4, float mo8,
                                          float w1, float w2) {
    float b;
    b = dppf<0x111, 0xF, 0xF, true >(v); v = fmaf(mo1, b, v); // row_shr:1
    b = dppf<0x112, 0xF, 0xF, true >(v); v = fmaf(mo2, b, v); // row_shr:2
    b = dppf<0x114, 0xF, 0xF, true >(v); v = fmaf(mo4, b, v); // row_shr:4
    b = dppf<0x118, 0xF, 0xF, true >(v); v = fmaf(mo8, b, v); // row_shr:8
    b = dppf<0x142, 0xA, 0xF, false>(v); v = fmaf(w1,  b, v); // row_bcast:15
    b = dppf<0x143, 0xC, 0xF, false>(v); v = fmaf(w2,  b, v); // row_bcast:31
    return v;
}

__device__ __forceinline__ float shape(float xs, int ty, float g, float dc,
                                       float c1, float c0) {
    if (ty == 0) {
        // tanh(p) = 1 - 2/(exp(2p)+1), exp folded: e2 = 2^(xs*c1 + c0)
        float e2 = __builtin_amdgcn_exp2f(fmaf(xs, c1, c0));
        return fmaf(-2.0f, __builtin_amdgcn_rcpf(e2 + 1.0f), 1.0f);
    }
    float p = (xs + dc) * g;
    if (ty == 1) {
        return fminf(fmaxf(p, -1.0f), 1.0f);
    } else if (ty == 2) {
        float r = p + 1.0f;
        float rem = r - 4.0f * floorf(r * 0.25f);   // jnp.remainder(r, 4)
        return fabsf(rem - 2.0f) - 1.0f;
    } else if (ty == 3) {
        return __sinf(p * 1.5707963267948966f);
    } else {
        return p / (1.0f + fabsf(p));
    }
}

__device__ __forceinline__ void load_chunk(v4f xv[4], const float* __restrict__ xr,
                                           int base, int N) {
    #pragma unroll
    for (int k = 0; k < 4; ++k) {
        const int j = base + k * 256;
        if (j + 4 <= N) {
            xv[k] = *reinterpret_cast<const v4f*>(xr + j);
        } else {
            xv[k].x = (j + 0 < N) ? xr[j + 0] : 0.0f;
            xv[k].y = (j + 1 < N) ? xr[j + 1] : 0.0f;
            xv[k].z = (j + 2 < N) ? xr[j + 2] : 0.0f;
            xv[k].w = (j + 3 < N) ? xr[j + 3] : 0.0f;
        }
    }
}

__global__ void __launch_bounds__(TPB, 6)
dist_kernel(const float* __restrict__ x,
            const float* __restrict__ drive,
            const float* __restrict__ bias,
            const float* __restrict__ mix,
            const int* __restrict__ type_idx,
            float* __restrict__ out,
            int N, float alpha, float beta)
{
    const int row  = blockIdx.y;
    const int bx   = blockIdx.x;
    const int tid  = threadIdx.x;
    const int lane = tid & 63;
    const int wv   = tid >> 6;
    const int ty   = *type_idx;   // wave-uniform

    const int nChunks = (N + CHUNK - 1) / CHUNK;
    const int cpb = (nChunks + NB - 1) / NB;
    const int cFirst = bx * cpb;
    if (cFirst >= nChunks) return;              // uniform: whole block exits
    const int cLast = min(cFirst + cpb, nChunks);
    const int spanStart = cFirst * CHUNK;

    const float g  = exp2f(drive[row] * 7.972672880099267f);  // 10^(2.4*drive)
    const float dc = bias[row] * 2.0f - 1.0f;
    const float mm = mix[row];
    const float om = 1.0f - mm;
    const float c1 = g * 2.8853900817779268f;   // 2*log2(e)*g
    const float c0 = dc * c1;

    const long long rowBase = (long long)row * (long long)N;
    const float* __restrict__ xr = x + rowBase;
    float* __restrict__ outr = out + rowBase;

    // alpha power ladder
    const float A2 = alpha * alpha;
    const float A4 = A2 * A2;
    const float A8 = A4 * A4;
    const float A16 = A8 * A8;
    const float A32 = A16 * A16;
    const float A64 = A32 * A32;
    const float A128 = A64 * A64;
    const float A256 = A128 * A128;
    const float A512 = A256 * A256;
    const float A1024 = A512 * A512;

    // per-lane multipliers: p15 = A4^(lane&15), apl = A4^lane
    float p15 = 1.0f;
    {
        float b = A4; const int n = lane & 15;
        #pragma unroll
        for (int i = 0; i < 4; ++i) { if ((n >> i) & 1) p15 *= b; b *= b; }
    }
    const float p31 = (lane & 16) ? p15 * A64  : p15;   // A4^(lane&31)
    const float apl = (lane & 32) ? p31 * A128 : p31;   // A4^lane
    const float w1 = A4 * p15;                          // A4^((lane&15)+1)
    const float w2 = A4 * p31;                          // A4^((lane&31)+1)

    __shared__ float wtot[2][WAVES];
    const int wvOff = wv * PER_WAVE + lane * 4;

    // issue chunk-0 loads first; they fly during the halo prologue
    v4f xc[4];
    load_chunk(xc, xr, spanStart + wvOff, N);

    // ---- halo prologue: z entering the span (bx==0: exact zero) ----
    float carry = 0.0f;
    if (bx > 0) {
        // HALO = 8 waves x 256 elems; lane owns 4 elems (in-bounds for bx>0)
        const int j = spanStart - HALO + wv * 256 + lane * 4;
        const v4f hx = *reinterpret_cast<const v4f*>(xr + j);
        float r = shape(hx.x, ty, g, dc, c1, c0);
        r = fmaf(alpha, r, shape(hx.y, ty, g, dc, c1, c0));
        r = fmaf(alpha, r, shape(hx.z, ty, g, dc, c1, c0));
        r = fmaf(alpha, r, shape(hx.w, ty, g, dc, c1, c0));
        const float s = scan_iir(r, A4, A8, A16, A32, w1, w2);
        if (lane == 63) wtot[1][wv] = s;        // wave total = lane63 scan
    }
    __syncthreads();
    if (bx > 0) {
        #pragma unroll
        for (int w = 0; w < WAVES; ++w) carry = fmaf(A256, carry, wtot[1][w]);
    }

    // ---- main loop over the span's chunks; z carries exactly ----
    int par = 0;
    for (int c = cFirst; c < cLast; ++c, par ^= 1) {
        const int cb = c * CHUNK;
        const bool more = (c + 1 < cLast);
        v4f xn[4];
        if (more) load_chunk(xn, xr, cb + CHUNK + wvOff, N);  // prefetch t+1

        // waveshape
        v4f d4[4];
        #pragma unroll
        for (int k = 0; k < 4; ++k) {
            d4[k].x = shape(xc[k].x, ty, g, dc, c1, c0);
            d4[k].y = shape(xc[k].y, ty, g, dc, c1, c0);
            d4[k].z = shape(xc[k].z, ty, g, dc, c1, c0);
            d4[k].w = shape(xc[k].w, ty, g, dc, c1, c0);
        }

        // run summaries (4 elems, mult alpha) + wave scans (mult A4)
        float iv[4];
        #pragma unroll
        for (int k = 0; k < 4; ++k) {
            float acc = d4[k].x;
            acc = fmaf(alpha, acc, d4[k].y);
            acc = fmaf(alpha, acc, d4[k].z);
            acc = fmaf(alpha, acc, d4[k].w);
            iv[k] = scan_iir(acc, A4, A8, A16, A32, w1, w2);
        }

        // sub-block totals (lane 63 -> SGPR) & wave total
        float Tk[4];
        #pragma unroll
        for (int k = 0; k < 4; ++k) Tk[k] = readlane_f(iv[k], 63);
        const float Twave =
            fmaf(A256, fmaf(A256, fmaf(A256, Tk[0], Tk[1]), Tk[2]), Tk[3]);
        if (lane == 0) wtot[par][wv] = Twave;
        __syncthreads();

        // z entering this wave (P), and carry update for next chunk
        float P = carry;
        for (int w = 0; w < wv; ++w) P = fmaf(A1024, P, wtot[par][w]);
        #pragma unroll
        for (int w = 0; w < WAVES; ++w) carry = fmaf(A1024, carry, wtot[par][w]);

        // ---- phase C: y[i] = d[i] - beta*z[i-1]; out = om*x + mm*y ----
        float S = 0.0f, aK = 1.0f;
        #pragma unroll
        for (int k = 0; k < 4; ++k) {
            const int j = cb + wvOff + k * 256;
            const float Ck = fmaf(aK, P, S);              // z entering sub-blk k
            // exclusive lane scan = previous lane's inclusive scan (lane0: 0)
            const float ex = dppf<0x138, 0xF, 0xF, true>(iv[k]); // wave_shr:1
            float z = fmaf(apl, Ck, ex);                  // z before lane's run
            v4f ov; float y;
            y = fmaf(-beta, z, d4[k].x); ov.x = fmaf(mm, y, om * xc[k].x); z = fmaf(alpha, z, d4[k].x);
            y = fmaf(-beta, z, d4[k].y); ov.y = fmaf(mm, y, om * xc[k].y); z = fmaf(alpha, z, d4[k].y);
            y = fmaf(-beta, z, d4[k].z); ov.z = fmaf(mm, y, om * xc[k].z); z = fmaf(alpha, z, d4[k].z);
            y = fmaf(-beta, z, d4[k].w); ov.w = fmaf(mm, y, om * xc[k].w);
            if (j + 4 <= N) {
                __builtin_nontemporal_store(ov, reinterpret_cast<v4f*>(outr + j));
            } else {
                if (j + 0 < N) outr[j + 0] = ov.x;
                if (j + 1 < N) outr[j + 1] = ov.y;
                if (j + 2 < N) outr[j + 2] = ov.z;
                if (j + 3 < N) outr[j + 3] = ov.w;
            }
            S = fmaf(A256, S, Tk[k]);
            aK *= A256;
        }

        if (more) {
            #pragma unroll
            for (int k = 0; k < 4; ++k) xc[k] = xn[k];
        }
    }
}

extern "C" void kernel_launch(void* const* d_in, const int* in_sizes, int n_in,
                              void* d_out, int out_size, void* d_ws, size_t ws_size,
                              hipStream_t stream) {
    const float* x     = (const float*)d_in[0];
    const float* drive = (const float*)d_in[1];
    const float* bias  = (const float*)d_in[2];
    const float* mixp  = (const float*)d_in[3];
    const int*   tyi   = (const int*)d_in[4];
    float* out = (float*)d_out;

    const int B = in_sizes[1];              // drive is (B,1)
    const int N = in_sizes[0] / B;

    const double alpha_d = exp(-2.0 * M_PI * 20.0 / 44100.0);
    const float alpha = (float)alpha_d;
    const float beta  = (float)(1.0 - alpha_d);

    dim3 grid(NB, B);
    dist_kernel<<<grid, TPB, 0, stream>>>(x, drive, bias, mixp, tyi, out, N, alpha, beta);
}

// Round 3
// 117.781 us; speedup vs baseline: 1.1731x; 1.1731x over previous
//
#include <hip/hip_runtime.h>
#include <math.h>

// Persistent-span chunked parallel IIR (z-formulation):
//   z[i] = alpha*z[i-1] + d[i];  y[i] = d[i] - (1-alpha)*z[i-1]
// R3: LDS data plane. R2 showed the register-resident chunk buffers force
// either low occupancy (512,4 -> 2 blk/CU) or scratch spills (512,6: +26.6MB
// WRITE_SIZE, 13 dwords/thread). Fix: stage x-chunks into LDS via
// global_load_lds (width 16, linear layout = wave-uniform base + lane*16),
// and recompute shape() in phase C instead of keeping d4[] live. Persistent
// regs ~= iv[2] + constants -> fits 85-reg budget (512,6) with margin; LDS
// 2 x 16KB dbuf = 32.8KB/block -> 3-4 blocks/CU resident.
// STAGE(t+1) issues after the compose barrier so HBM latency hides under
// phase C; the end-of-iter __syncthreads doubles as the vmcnt drain.
// Span = 4 chunks of 4096; halo paid once per span (read amp 12.5%).
#define TPB 512
#define WAVES (TPB / 64)          // 8
#define PER_WAVE 512              // elements per wave per chunk
#define CHUNK (WAVES * PER_WAVE)  // 4096 floats = 16 KB
#define NB 16                     // spans per row; span = 16384 elems
#define HALO 2048                 // alpha^2048 ~ 2.9e-3, error << 0.1075 thr

typedef float v4f __attribute__((ext_vector_type(4)));

template<int CTRL, int RM, int BM, bool BC>
__device__ __forceinline__ float dppf(float v) {
    return __int_as_float(__builtin_amdgcn_update_dpp(
        0, __float_as_int(v), CTRL, RM, BM, BC));
}

__device__ __forceinline__ float readlane_f(float v, int l) {
    return __int_as_float(__builtin_amdgcn_readlane(__float_as_int(v), l));
}

// global -> LDS direct copy, 16B per lane. LDS dest is wave-uniform base
// (+ lane*16 by HW); global src is per-lane. Layout is linear on both sides.
__device__ __forceinline__ void stage16(const float* __restrict__ g, float* l) {
    __builtin_amdgcn_global_load_lds(
        (const __attribute__((address_space(1))) unsigned int*)g,
        (__attribute__((address_space(3))) unsigned int*)l, 16, 0, 0);
}

// Weighted inclusive scan over 64 lanes: S_l = sum_{k<=l} m^(l-k) * v_k, m=A4.
// row_shr 1/2/4/8 (within-16 scan), row_bcast:15 (rows 1,3 += w1 * prev-row
// prefix), row_bcast:31 (rows 2,3 += w2 * S_31).
// w1 = m^((lane&15)+1), w2 = m^((lane&31)+1).
__device__ __forceinline__ float scan_iir(float v, float mo1, float mo2,
                                          float mo4, float mo8,
                                          float w1, float w2) {
    float b;
    b = dppf<0x111, 0xF, 0xF, true >(v); v = fmaf(mo1, b, v); // row_shr:1
    b = dppf<0x112, 0xF, 0xF, true >(v); v = fmaf(mo2, b, v); // row_shr:2
    b = dppf<0x114, 0xF, 0xF, true >(v); v = fmaf(mo4, b, v); // row_shr:4
    b = dppf<0x118, 0xF, 0xF, true >(v); v = fmaf(mo8, b, v); // row_shr:8
    b = dppf<0x142, 0xA, 0xF, false>(v); v = fmaf(w1,  b, v); // row_bcast:15
    b = dppf<0x143, 0xC, 0xF, false>(v); v = fmaf(w2,  b, v); // row_bcast:31
    return v;
}

__device__ __forceinline__ float shape(float xs, int ty, float g, float dc,
                                       float c1, float c0) {
    if (ty == 0) {
        // tanh(p) = 1 - 2/(exp(2p)+1), exp folded: e2 = 2^(xs*c1 + c0)
        float e2 = __builtin_amdgcn_exp2f(fmaf(xs, c1, c0));
        return fmaf(-2.0f, __builtin_amdgcn_rcpf(e2 + 1.0f), 1.0f);
    }
    float p = (xs + dc) * g;
    if (ty == 1) {
        return fminf(fmaxf(p, -1.0f), 1.0f);
    } else if (ty == 2) {
        float r = p + 1.0f;
        float rem = r - 4.0f * floorf(r * 0.25f);   // jnp.remainder(r, 4)
        return fabsf(rem - 2.0f) - 1.0f;
    } else if (ty == 3) {
        return __sinf(p * 1.5707963267948966f);
    } else {
        return p / (1.0f + fabsf(p));
    }
}

__global__ void __launch_bounds__(TPB, 6)
dist_kernel(const float* __restrict__ x,
            const float* __restrict__ drive,
            const float* __restrict__ bias,
            const float* __restrict__ mix,
            const int* __restrict__ type_idx,
            float* __restrict__ out,
            int N, float alpha, float beta)
{
    const int row  = blockIdx.y;
    const int bx   = blockIdx.x;
    const int tid  = threadIdx.x;
    const int lane = tid & 63;
    const int wv   = tid >> 6;
    const int ty   = *type_idx;   // wave-uniform

    const int nChunks = (N + CHUNK - 1) / CHUNK;
    const int cpb = (nChunks + NB - 1) / NB;
    const int cFirst = bx * cpb;
    if (cFirst >= nChunks) return;              // uniform: whole block exits
    const int cLast = min(cFirst + cpb, nChunks);
    const int spanStart = cFirst * CHUNK;

    const long long rowBase = (long long)row * (long long)N;
    const float* __restrict__ xr = x + rowBase;
    float* __restrict__ outr = out + rowBase;

    __shared__ float sbuf[2][CHUNK];
    __shared__ float wtot[2][WAVES];

    const int ldsBase = wv * PER_WAVE;          // wave-uniform, floats
    const int wvOff   = ldsBase + lane * 4;     // per-lane, floats

    // ---- stage first chunk into sbuf[0] ASAP (flies during prologue) ----
    if (spanStart + CHUNK <= N) {
        stage16(xr + spanStart + ldsBase + lane * 4,       &sbuf[0][ldsBase]);
        stage16(xr + spanStart + ldsBase + 256 + lane * 4, &sbuf[0][ldsBase + 256]);
    } else {
        #pragma unroll
        for (int h = 0; h < 2; ++h) {
            const int idx = ldsBase + h * 256 + lane * 4;
            const int j = spanStart + idx;
            v4f v;
            v.x = (j + 0 < N) ? xr[j + 0] : 0.0f;
            v.y = (j + 1 < N) ? xr[j + 1] : 0.0f;
            v.z = (j + 2 < N) ? xr[j + 2] : 0.0f;
            v.w = (j + 3 < N) ? xr[j + 3] : 0.0f;
            *reinterpret_cast<v4f*>(&sbuf[0][idx]) = v;
        }
    }

    const float g  = exp2f(drive[row] * 7.972672880099267f);  // 10^(2.4*drive)
    const float dc = bias[row] * 2.0f - 1.0f;
    const float mm = mix[row];
    const float om = 1.0f - mm;
    const float c1 = g * 2.8853900817779268f;   // 2*log2(e)*g
    const float c0 = dc * c1;

    // alpha power ladder
    const float A2 = alpha * alpha;
    const float A4 = A2 * A2;
    const float A8 = A4 * A4;
    const float A16 = A8 * A8;
    const float A32 = A16 * A16;
    const float A64 = A32 * A32;
    const float A128 = A64 * A64;
    const float A256 = A128 * A128;
    const float A512 = A256 * A256;

    // per-lane multipliers: p15 = A4^(lane&15), apl = A4^lane
    float p15 = 1.0f;
    {
        float b = A4; const int n = lane & 15;
        #pragma unroll
        for (int i = 0; i < 4; ++i) { if ((n >> i) & 1) p15 *= b; b *= b; }
    }
    const float p31 = (lane & 16) ? p15 * A64  : p15;   // A4^(lane&31)
    const float apl = (lane & 32) ? p31 * A128 : p31;   // A4^lane
    const float w1 = A4 * p15;                          // A4^((lane&15)+1)
    const float w2 = A4 * p31;                          // A4^((lane&31)+1)

    // ---- halo prologue: z entering the span (bx==0: exact zero) ----
    float carry = 0.0f;
    if (bx > 0) {
        // HALO = 8 waves x 256 elems; lane owns 4 elems (in-bounds for bx>0)
        const int j = spanStart - HALO + wv * 256 + lane * 4;
        const v4f hx = *reinterpret_cast<const v4f*>(xr + j);
        float r = shape(hx.x, ty, g, dc, c1, c0);
        r = fmaf(alpha, r, shape(hx.y, ty, g, dc, c1, c0));
        r = fmaf(alpha, r, shape(hx.z, ty, g, dc, c1, c0));
        r = fmaf(alpha, r, shape(hx.w, ty, g, dc, c1, c0));
        const float s = scan_iir(r, A4, A8, A16, A32, w1, w2);
        if (lane == 63) wtot[1][wv] = s;        // wave total = lane63 scan
    }
    __syncthreads();   // drains stage(chunk 0) + halo loads; wtot[1] visible
    if (bx > 0) {
        #pragma unroll
        for (int w = 0; w < WAVES; ++w) carry = fmaf(A256, carry, wtot[1][w]);
    }

    // ---- main loop; z carries exactly across the span's chunks ----
    int par = 0;
    for (int c = cFirst; c < cLast; ++c, par ^= 1) {
        const int cb = c * CHUNK;

        // phase A: shape + run summary + wave scan, data from LDS
        float iv[2];
        #pragma unroll
        for (int k = 0; k < 2; ++k) {
            const v4f xv = *reinterpret_cast<const v4f*>(&sbuf[par][wvOff + k * 256]);
            float acc = shape(xv.x, ty, g, dc, c1, c0);
            acc = fmaf(alpha, acc, shape(xv.y, ty, g, dc, c1, c0));
            acc = fmaf(alpha, acc, shape(xv.z, ty, g, dc, c1, c0));
            acc = fmaf(alpha, acc, shape(xv.w, ty, g, dc, c1, c0));
            iv[k] = scan_iir(acc, A4, A8, A16, A32, w1, w2);
        }
        const float Tk0 = readlane_f(iv[0], 63);
        const float Tk1 = readlane_f(iv[1], 63);
        if (lane == 0) wtot[par][wv] = fmaf(A256, Tk0, Tk1);   // 512-elem total
        __syncthreads();                       // (1) wtot visible

        // z entering this wave (P) and carry into next chunk
        float P = carry;
        for (int w = 0; w < wv; ++w) P = fmaf(A512, P, wtot[par][w]);
        #pragma unroll
        for (int w = 0; w < WAVES; ++w) carry = fmaf(A512, carry, wtot[par][w]);

        // stage chunk c+1 into the other buffer; latency hides under phase C.
        // WAR-safe: its previous readers finished at barrier (2) of iter c-1.
        if (c + 1 < cLast) {
            const int nb = cb + CHUNK;
            if (nb + CHUNK <= N) {
                stage16(xr + nb + ldsBase + lane * 4,       &sbuf[par ^ 1][ldsBase]);
                stage16(xr + nb + ldsBase + 256 + lane * 4, &sbuf[par ^ 1][ldsBase + 256]);
            } else {
                #pragma unroll
                for (int h = 0; h < 2; ++h) {
                    const int idx = ldsBase + h * 256 + lane * 4;
                    const int j = nb + idx;
                    v4f v;
                    v.x = (j + 0 < N) ? xr[j + 0] : 0.0f;
                    v.y = (j + 1 < N) ? xr[j + 1] : 0.0f;
                    v.z = (j + 2 < N) ? xr[j + 2] : 0.0f;
                    v.w = (j + 3 < N) ? xr[j + 3] : 0.0f;
                    *reinterpret_cast<v4f*>(&sbuf[par ^ 1][idx]) = v;
                }
            }
        }

        // phase C: re-read x from LDS, recompute shape, emit output
        float S = 0.0f, aK = 1.0f;
        #pragma unroll
        for (int k = 0; k < 2; ++k) {
            const int j = cb + wvOff + k * 256;
            const v4f xv = *reinterpret_cast<const v4f*>(&sbuf[par][wvOff + k * 256]);
            const float d0 = shape(xv.x, ty, g, dc, c1, c0);
            const float d1 = shape(xv.y, ty, g, dc, c1, c0);
            const float d2 = shape(xv.z, ty, g, dc, c1, c0);
            const float d3 = shape(xv.w, ty, g, dc, c1, c0);
            const float Ck = fmaf(aK, P, S);              // z entering sub-blk k
            // exclusive lane scan = previous lane's inclusive scan (lane0: 0)
            const float ex = dppf<0x138, 0xF, 0xF, true>(iv[k]); // wave_shr:1
            float z = fmaf(apl, Ck, ex);                  // z before lane's run
            v4f ov; float y;
            y = fmaf(-beta, z, d0); ov.x = fmaf(mm, y, om * xv.x); z = fmaf(alpha, z, d0);
            y = fmaf(-beta, z, d1); ov.y = fmaf(mm, y, om * xv.y); z = fmaf(alpha, z, d1);
            y = fmaf(-beta, z, d2); ov.z = fmaf(mm, y, om * xv.z); z = fmaf(alpha, z, d2);
            y = fmaf(-beta, z, d3); ov.w = fmaf(mm, y, om * xv.w);
            if (j + 4 <= N) {
                __builtin_nontemporal_store(ov, reinterpret_cast<v4f*>(outr + j));
            } else {
                if (j + 0 < N) outr[j + 0] = ov.x;
                if (j + 1 < N) outr[j + 1] = ov.y;
                if (j + 2 < N) outr[j + 2] = ov.z;
                if (j + 3 < N) outr[j + 3] = ov.w;
            }
            S = fmaf(A256, S, Tk0);
            aK *= A256;
        }
        __syncthreads();   // (2) buf[par^1] staged (vmcnt drain) + reads done
    }
}

extern "C" void kernel_launch(void* const* d_in, const int* in_sizes, int n_in,
                              void* d_out, int out_size, void* d_ws, size_t ws_size,
                              hipStream_t stream) {
    const float* x     = (const float*)d_in[0];
    const float* drive = (const float*)d_in[1];
    const float* bias  = (const float*)d_in[2];
    const float* mixp  = (const float*)d_in[3];
    const int*   tyi   = (const int*)d_in[4];
    float* out = (float*)d_out;

    const int B = in_sizes[1];              // drive is (B,1)
    const int N = in_sizes[0] / B;

    const double alpha_d = exp(-2.0 * M_PI * 20.0 / 44100.0);
    const float alpha = (float)alpha_d;
    const float beta  = (float)(1.0 - alpha_d);

    dim3 grid(NB, B);
    dist_kernel<<<grid, TPB, 0, stream>>>(x, drive, bias, mixp, tyi, out, N, alpha, beta);
}

// Round 4
// 116.316 us; speedup vs baseline: 1.1879x; 1.0126x over previous
//
#include <hip/hip_runtime.h>
#include <math.h>

// One-shot span parallel IIR (z-formulation):
//   z[i] = alpha*z[i-1] + d[i];  y[i] = d[i] - (1-alpha)*z[i-1]
// R4: kill the per-chunk barriers. R1 (register dbuf, 16 waves/CU) and R3
// (LDS dbuf, more waves) both landed at ~33us -> the invariant is the
// per-chunk __syncthreads, whose vmcnt(0) drains the phase-C STORES every
// 16KB (store-ACK stall, ~30% bubble vs the 22.6us traffic floor).
// New structure: each block does ONE span, exactly 2 barriers, stores last:
//   stage span+halo (global_load_lds burst) -> barrier -> halo scan + wave
//   scans (VALU/DPP on LDS) -> barrier -> compose + phase C + nt-stores ->
//   endpgm. Stores never precede a barrier; they drain as the block retires.
// LDS = (8192+2048)*4 = 40960 B exactly -> 4 blocks/CU (163840/40960=4.0);
// scan totals live in dead halo slots to avoid LDS rounding to 41.5KB.
// Grid = 32 x 64 = 2048 blocks = 2 exact resident rounds.
#define TPB 512
#define WAVES (TPB / 64)          // 8
#define SPAN 8192                 // output elems per block
#define HALO 2048                 // alpha^2048 ~ 2.9e-3 << 0.1075 threshold
#define TOT (SPAN + HALO)         // 10240 floats staged = 40960 B LDS
#define WSPAN (SPAN / WAVES)      // 1024 floats per wave = 4 sub-blocks of 256

typedef float v4f __attribute__((ext_vector_type(4)));

template<int CTRL, int RM, int BM, bool BC>
__device__ __forceinline__ float dppf(float v) {
    return __int_as_float(__builtin_amdgcn_update_dpp(
        0, __float_as_int(v), CTRL, RM, BM, BC));
}

__device__ __forceinline__ float readlane_f(float v, int l) {
    return __int_as_float(__builtin_amdgcn_readlane(__float_as_int(v), l));
}

// global -> LDS direct copy, 16B per lane. LDS dest is wave-uniform base
// (+ lane*16 by HW); global src is per-lane. Linear on both sides.
__device__ __forceinline__ void stage16(const float* __restrict__ g, float* l) {
    __builtin_amdgcn_global_load_lds(
        (const __attribute__((address_space(1))) unsigned int*)g,
        (__attribute__((address_space(3))) unsigned int*)l, 16, 0, 0);
}

// Weighted inclusive scan over 64 lanes: S_l = sum_{k<=l} m^(l-k) * v_k, m=A4.
// row_shr 1/2/4/8 (within-16 scan), row_bcast:15 (rows 1,3 += w1 * prev-row
// prefix), row_bcast:31 (rows 2,3 += w2 * S_31).
// w1 = m^((lane&15)+1), w2 = m^((lane&31)+1).
__device__ __forceinline__ float scan_iir(float v, float mo1, float mo2,
                                          float mo4, float mo8,
                                          float w1, float w2) {
    float b;
    b = dppf<0x111, 0xF, 0xF, true >(v); v = fmaf(mo1, b, v); // row_shr:1
    b = dppf<0x112, 0xF, 0xF, true >(v); v = fmaf(mo2, b, v); // row_shr:2
    b = dppf<0x114, 0xF, 0xF, true >(v); v = fmaf(mo4, b, v); // row_shr:4
    b = dppf<0x118, 0xF, 0xF, true >(v); v = fmaf(mo8, b, v); // row_shr:8
    b = dppf<0x142, 0xA, 0xF, false>(v); v = fmaf(w1,  b, v); // row_bcast:15
    b = dppf<0x143, 0xC, 0xF, false>(v); v = fmaf(w2,  b, v); // row_bcast:31
    return v;
}

__device__ __forceinline__ float shape(float xs, int ty, float g, float dc,
                                       float c1, float c0) {
    if (ty == 0) {
        // tanh(p) = 1 - 2/(exp(2p)+1), exp folded: e2 = 2^(xs*c1 + c0)
        float e2 = __builtin_amdgcn_exp2f(fmaf(xs, c1, c0));
        return fmaf(-2.0f, __builtin_amdgcn_rcpf(e2 + 1.0f), 1.0f);
    }
    float p = (xs + dc) * g;
    if (ty == 1) {
        return fminf(fmaxf(p, -1.0f), 1.0f);
    } else if (ty == 2) {
        float r = p + 1.0f;
        float rem = r - 4.0f * floorf(r * 0.25f);   // jnp.remainder(r, 4)
        return fabsf(rem - 2.0f) - 1.0f;
    } else if (ty == 3) {
        return __sinf(p * 1.5707963267948966f);
    } else {
        return p / (1.0f + fabsf(p));
    }
}

__global__ void __launch_bounds__(TPB, 6)
dist_kernel(const float* __restrict__ x,
            const float* __restrict__ drive,
            const float* __restrict__ bias,
            const float* __restrict__ mix,
            const int* __restrict__ type_idx,
            float* __restrict__ out,
            int N, float alpha, float beta)
{
    const int row  = blockIdx.y;
    const int bx   = blockIdx.x;
    const int tid  = threadIdx.x;
    const int lane = tid & 63;
    const int wv   = tid >> 6;
    const int ty   = *type_idx;   // wave-uniform

    const int spanStart = bx * SPAN;

    const long long rowBase = (long long)row * (long long)N;
    const float* __restrict__ xr = x + rowBase;
    float* __restrict__ outr = out + rowBase;

    // sbuf[p] mirrors x[spanStart - HALO + p]; halo part staged only if bx>0.
    __shared__ float sbuf[TOT];

    // ---- staging burst: deep queue of 1KB global_load_lds ----
    const bool fullSpan = (spanStart + SPAN <= N);
    if (fullSpan) {
        if (bx > 0) {                       // halo+span: 1280 floats/wave
            const int gb = spanStart - HALO + wv * (TOT / WAVES);
            const int lb = wv * (TOT / WAVES);
            #pragma unroll
            for (int i = 0; i < (TOT / WAVES) / 256; ++i)   // 5
                stage16(xr + gb + i * 256 + lane * 4, &sbuf[lb + i * 256]);
        } else {                            // span only: 1024 floats/wave
            const int gb = spanStart + wv * WSPAN;
            const int lb = HALO + wv * WSPAN;
            #pragma unroll
            for (int i = 0; i < WSPAN / 256; ++i)           // 4
                stage16(xr + gb + i * 256 + lane * 4, &sbuf[lb + i * 256]);
        }
    } else {
        // guarded fallback (partial span / small N): v4f-granular ds writes
        for (int p = tid * 4; p < TOT; p += TPB * 4) {
            const int j = spanStart - HALO + p;
            v4f v;
            v.x = (j + 0 >= 0 && j + 0 < N) ? xr[j + 0] : 0.0f;
            v.y = (j + 1 >= 0 && j + 1 < N) ? xr[j + 1] : 0.0f;
            v.z = (j + 2 >= 0 && j + 2 < N) ? xr[j + 2] : 0.0f;
            v.w = (j + 3 >= 0 && j + 3 < N) ? xr[j + 3] : 0.0f;
            *reinterpret_cast<v4f*>(&sbuf[p]) = v;
        }
    }

    // row params + constants (overlap with staging flight)
    const float g  = exp2f(drive[row] * 7.972672880099267f);  // 10^(2.4*drive)
    const float dc = bias[row] * 2.0f - 1.0f;
    const float mm = mix[row];
    const float om = 1.0f - mm;
    const float c1 = g * 2.8853900817779268f;   // 2*log2(e)*g
    const float c0 = dc * c1;

    const float A2 = alpha * alpha;
    const float A4 = A2 * A2;
    const float A8 = A4 * A4;
    const float A16 = A8 * A8;
    const float A32 = A16 * A16;
    const float A64 = A32 * A32;
    const float A128 = A64 * A64;
    const float A256 = A128 * A128;
    const float A512 = A256 * A256;
    const float A1024 = A512 * A512;

    // per-lane multipliers: p15 = A4^(lane&15), apl = A4^lane
    float p15 = 1.0f;
    {
        float b = A4; const int n = lane & 15;
        #pragma unroll
        for (int i = 0; i < 4; ++i) { if ((n >> i) & 1) p15 *= b; b *= b; }
    }
    const float p31 = (lane & 16) ? p15 * A64  : p15;   // A4^(lane&31)
    const float apl = (lane & 32) ? p31 * A128 : p31;   // A4^lane
    const float w1 = A4 * p15;                          // A4^((lane&15)+1)
    const float w2 = A4 * p31;                          // A4^((lane&31)+1)

    __syncthreads();   // (1) staging visible (drains global_load_lds)

    // ---- halo scan: wave w scans halo sub-block w (256 floats) ----
    // Th parked at sbuf[wv*256] — a slot this wave just finished reading;
    // no other wave reads the halo area, so no race. (bx==0: skipped, carry=0)
    if (bx > 0) {
        const v4f hx = *reinterpret_cast<const v4f*>(&sbuf[wv * 256 + lane * 4]);
        float r = shape(hx.x, ty, g, dc, c1, c0);
        r = fmaf(alpha, r, shape(hx.y, ty, g, dc, c1, c0));
        r = fmaf(alpha, r, shape(hx.z, ty, g, dc, c1, c0));
        r = fmaf(alpha, r, shape(hx.w, ty, g, dc, c1, c0));
        const float s = scan_iir(r, A4, A8, A16, A32, w1, w2);
        if (lane == 63) sbuf[wv * 256] = s;
    }

    // ---- span scans: wave w owns 1024 floats = 4 sub-blocks of 256 ----
    float iv[4], Tk[4];
    #pragma unroll
    for (int k = 0; k < 4; ++k) {
        const v4f xv = *reinterpret_cast<const v4f*>(
            &sbuf[HALO + wv * WSPAN + k * 256 + lane * 4]);
        float acc = shape(xv.x, ty, g, dc, c1, c0);
        acc = fmaf(alpha, acc, shape(xv.y, ty, g, dc, c1, c0));
        acc = fmaf(alpha, acc, shape(xv.z, ty, g, dc, c1, c0));
        acc = fmaf(alpha, acc, shape(xv.w, ty, g, dc, c1, c0));
        iv[k] = scan_iir(acc, A4, A8, A16, A32, w1, w2);
        Tk[k] = readlane_f(iv[k], 63);
    }
    const float Tw =
        fmaf(A256, fmaf(A256, fmaf(A256, Tk[0], Tk[1]), Tk[2]), Tk[3]);
    if (lane == 0) sbuf[wv * 256 + 1] = Tw;   // dead halo slot (own sub-block)
    __syncthreads();   // (2) totals visible; no stores issued yet

    // ---- compose: carry at spanStart, P = z entering this wave's region ----
    float carry = 0.0f;
    if (bx > 0) {
        #pragma unroll
        for (int w = 0; w < WAVES; ++w)
            carry = fmaf(A256, carry, sbuf[w * 256]);
    }
    float P = carry;
    for (int w = 0; w < wv; ++w) P = fmaf(A1024, P, sbuf[w * 256 + 1]);

    // ---- phase C: y[i] = d[i] - beta*z[i-1]; out = om*x + mm*y; stores last ----
    float S = 0.0f, aK = 1.0f;
    #pragma unroll
    for (int k = 0; k < 4; ++k) {
        const int j = spanStart + wv * WSPAN + k * 256 + lane * 4;
        const v4f xv = *reinterpret_cast<const v4f*>(
            &sbuf[HALO + wv * WSPAN + k * 256 + lane * 4]);
        const float d0 = shape(xv.x, ty, g, dc, c1, c0);
        const float d1 = shape(xv.y, ty, g, dc, c1, c0);
        const float d2 = shape(xv.z, ty, g, dc, c1, c0);
        const float d3 = shape(xv.w, ty, g, dc, c1, c0);
        const float Ck = fmaf(aK, P, S);              // z entering sub-block k
        // exclusive lane scan = previous lane's inclusive scan (lane0: 0)
        const float ex = dppf<0x138, 0xF, 0xF, true>(iv[k]); // wave_shr:1
        float z = fmaf(apl, Ck, ex);                  // z before lane's run
        v4f ov; float y;
        y = fmaf(-beta, z, d0); ov.x = fmaf(mm, y, om * xv.x); z = fmaf(alpha, z, d0);
        y = fmaf(-beta, z, d1); ov.y = fmaf(mm, y, om * xv.y); z = fmaf(alpha, z, d1);
        y = fmaf(-beta, z, d2); ov.z = fmaf(mm, y, om * xv.z); z = fmaf(alpha, z, d2);
        y = fmaf(-beta, z, d3); ov.w = fmaf(mm, y, om * xv.w);
        if (j + 4 <= N) {
            __builtin_nontemporal_store(ov, reinterpret_cast<v4f*>(outr + j));
        } else {
            if (j + 0 < N) outr[j + 0] = ov.x;
            if (j + 1 < N) outr[j + 1] = ov.y;
            if (j + 2 < N) outr[j + 2] = ov.z;
            if (j + 3 < N) outr[j + 3] = ov.w;
        }
        S = fmaf(A256, S, Tk[k]);
        aK *= A256;
    }
    // no trailing barrier: stores drain as the block retires
}

extern "C" void kernel_launch(void* const* d_in, const int* in_sizes, int n_in,
                              void* d_out, int out_size, void* d_ws, size_t ws_size,
                              hipStream_t stream) {
    const float* x     = (const float*)d_in[0];
    const float* drive = (const float*)d_in[1];
    const float* bias  = (const float*)d_in[2];
    const float* mixp  = (const float*)d_in[3];
    const int*   tyi   = (const int*)d_in[4];
    float* out = (float*)d_out;

    const int B = in_sizes[1];              // drive is (B,1)
    const int N = in_sizes[0] / B;

    const double alpha_d = exp(-2.0 * M_PI * 20.0 / 44100.0);
    const float alpha = (float)alpha_d;
    const float beta  = (float)(1.0 - alpha_d);

    const int nSpans = (N + SPAN - 1) / SPAN;
    dim3 grid(nSpans, B);
    dist_kernel<<<grid, TPB, 0, stream>>>(x, drive, bias, mixp, tyi, out, N, alpha, beta);
}